// Round 6
// baseline (584.846 us; speedup 1.0000x reference)
//
#include <hip/hip_runtime.h>
#include <hip/hip_bf16.h>

#define D 64
#define KH 5
#define KS 6                        // chunk-list depth: pos + top-5 coverage
#define NCH 64                      // chunks (grid = 32*64 = 2048 blocks, 8/CU)
#define TPC 25                      // tiles per chunk
#define TILE 64
#define CHUNK_ITEMS (TPC * TILE)    // 1600; 64*1600 = 102400 >= N
#define CAP 24                      // candidate cap per (row,chunk)
#define CAPP 25                     // padded stride (odd -> conflict-free)
#define TMP 27                      // TM stride (odd)
#define NCAND (NCH * KS)            // 384 candidates per row at finalize

typedef _Float16 half8 __attribute__((ext_vector_type(8)));
typedef float f32x4 __attribute__((ext_vector_type(4)));

__device__ __forceinline__ bool better(float v, int vi, float w, int wi) {
    return (v > w) || (v == w && vi < wi);
}

__device__ __forceinline__ void top5_insert(float (&v)[KH], int (&ix)[KH], float nv, int ni) {
    if (better(nv, ni, v[KH - 1], ix[KH - 1])) {
        v[KH - 1] = nv; ix[KH - 1] = ni;
#pragma unroll
        for (int j = KH - 1; j > 0; --j) {
            if (better(v[j], ix[j], v[j - 1], ix[j - 1])) {
                float tf = v[j]; v[j] = v[j - 1]; v[j - 1] = tf;
                int   tI = ix[j]; ix[j] = ix[j - 1]; ix[j - 1] = tI;
            }
        }
    }
}

// ---------- prep: normalized fp16 table H[N][64] + fp32 inv_norm[N] ----------
// NT stores: keep lines out of the writer XCD's L2 (consumers fill their own L2)
__global__ void prep_kernel(const float* __restrict__ emb,
                            _Float16* __restrict__ H,
                            float* __restrict__ inv_norm, int N) {
    int tid = threadIdx.x;
    int wave = tid >> 6, lane = tid & 63;
    int item = blockIdx.x * 16 + wave * 4 + (lane >> 4);
    if (item >= N) return;
    int g = lane & 15;
    float4 v = reinterpret_cast<const float4*>(emb)[item * 16 + g];
    float ss = v.x * v.x + v.y * v.y + v.z * v.z + v.w * v.w;
#pragma unroll
    for (int m = 1; m < 16; m <<= 1) ss += __shfl_xor(ss, m, 64);
    float inv = 1.0f / fmaxf(sqrtf(ss), 1e-12f);
    union { _Float16 h[4]; unsigned long long u; } pk;
    pk.h[0] = (_Float16)(v.x * inv);
    pk.h[1] = (_Float16)(v.y * inv);
    pk.h[2] = (_Float16)(v.z * inv);
    pk.h[3] = (_Float16)(v.w * inv);
    __builtin_nontemporal_store(pk.u,
        reinterpret_cast<unsigned long long*>(H) + item * 16 + g);
    if (g == 0) __builtin_nontemporal_store(inv, inv_norm + item);
}

// ---------- main: two-pass tile-max thresholding (round-4 body, retuned) ----------
// grid 2048 (XCD-swizzled (rowblock, chunk)), block 256 = 4 waves, 8 blocks/CU.
__global__ __launch_bounds__(256, 8)
void simtopk_kernel(const _Float16* __restrict__ H,
                    const int* __restrict__ pos_items,
                    int* __restrict__ part_idx, int N) {
    __shared__ float TM[64][TMP];         // tile-max per row
    __shared__ float TH[64];              // per-row threshold (6th tile-max)
    __shared__ float CV[64][CAPP];
    __shared__ int   CI[64][CAPP];
    __shared__ int   CNT[64];

    const int tid = threadIdx.x;
    const int w = tid >> 6, lane = tid & 63;
    const int l15 = lane & 15, l4 = lane >> 4;

    // bijective XCD swizzle: ch%8 == blockIdx%8 == XCD -> L2-local item windows
    const int id = blockIdx.x;
    const int inner = id >> 3;
    const int ch = (id & 7) + 8 * (inner >> 5);
    const int rb = inner & 31;
    const int row0 = rb * 64;
    const int cbeg = ch * CHUNK_ITEMS;

    // B fragments: 4 groups x 16 user rows, register-resident (32 VGPR)
    half8 b0[4], b1[4];
#pragma unroll
    for (int g = 0; g < 4; ++g) {
        int ap = pos_items[row0 + g * 16 + l15];
        const half8* Hrow = (const half8*)(H + (size_t)ap * D);
        b0[g] = Hrow[l4];
        b1[g] = Hrow[4 + l4];
    }

    half8 A[8];
#define LOADA(t)                                                        \
    {                                                                   \
        int ib = cbeg + (t) * TILE;                                     \
        _Pragma("unroll")                                               \
        for (int sub = 0; sub < 4; ++sub) {                             \
            int it = min(ib + sub * 16 + l15, N - 1);                   \
            const half8* hp = (const half8*)(H + (size_t)it * D);       \
            A[2 * sub] = hp[l4];                                        \
            A[2 * sub + 1] = hp[4 + l4];                                \
        }                                                               \
    }

    // ---------------- pass 1: per-(row,tile) max — branchless ----------------
    for (int t = w; t < TPC; t += 4) {
        LOADA(t);
        const int ibase = cbeg + t * TILE;
        const bool ragged = (ibase + TILE > N);
        float rmax[4] = {-3e38f, -3e38f, -3e38f, -3e38f};
#pragma unroll
        for (int sub = 0; sub < 4; ++sub) {
            half8 a0 = A[2 * sub], a1 = A[2 * sub + 1];
            const int base_n = ibase + sub * 16 + 4 * l4;
#pragma unroll
            for (int g = 0; g < 4; ++g) {
                f32x4 z = {0.f, 0.f, 0.f, 0.f};
                f32x4 acc = __builtin_amdgcn_mfma_f32_16x16x32_f16(a0, b0[g], z, 0, 0, 0);
                acc = __builtin_amdgcn_mfma_f32_16x16x32_f16(a1, b1[g], acc, 0, 0, 0);
                if (ragged) {
#pragma unroll
                    for (int q = 0; q < 4; ++q)
                        if (base_n + q >= N) acc[q] = -3e38f;
                }
                rmax[g] = fmaxf(rmax[g],
                          fmaxf(fmaxf(acc[0], acc[1]), fmaxf(acc[2], acc[3])));
            }
        }
#pragma unroll
        for (int g = 0; g < 4; ++g) {
            float m = rmax[g];
            m = fmaxf(m, __shfl_xor(m, 16, 64));
            m = fmaxf(m, __shfl_xor(m, 32, 64));
            if (l4 == 0) TM[g * 16 + l15][t] = m;
        }
    }

    __syncthreads();

    // threshold phase: row's 6th-highest tile-max (values-only sort network)
    if (tid < 64) {
        float v[KS];
#pragma unroll
        for (int s = 0; s < KS; ++s) v[s] = -3e38f;
        for (int t = 0; t < TPC; ++t) {
            float x = TM[tid][t];
            if (x > v[KS - 1]) {
                v[KS - 1] = x;
#pragma unroll
                for (int j = KS - 1; j > 0; --j) {
                    float lo = fminf(v[j], v[j - 1]);
                    v[j - 1] = fmaxf(v[j], v[j - 1]);
                    v[j] = lo;
                }
            }
        }
        TH[tid] = v[KS - 1];
        CNT[tid] = 0;
    }
    __syncthreads();

    float thg[4];
#pragma unroll
    for (int g = 0; g < 4; ++g) thg[g] = TH[g * 16 + l15];

    // ---------------- pass 2: collect scores >= theta (bit-identical MFMA) ----------------
    for (int t = w; t < TPC; t += 4) {
        LOADA(t);
        const int ibase = cbeg + t * TILE;
#pragma unroll
        for (int sub = 0; sub < 4; ++sub) {
            half8 a0 = A[2 * sub], a1 = A[2 * sub + 1];
            const int base_n = ibase + sub * 16 + 4 * l4;
#pragma unroll
            for (int g = 0; g < 4; ++g) {
                f32x4 z = {0.f, 0.f, 0.f, 0.f};
                f32x4 acc = __builtin_amdgcn_mfma_f32_16x16x32_f16(a0, b0[g], z, 0, 0, 0);
                acc = __builtin_amdgcn_mfma_f32_16x16x32_f16(a1, b1[g], acc, 0, 0, 0);
                float m4 = fmaxf(fmaxf(acc[0], acc[1]), fmaxf(acc[2], acc[3]));
                if (m4 >= thg[g]) {
                    const int row = g * 16 + l15;
#pragma unroll
                    for (int q = 0; q < 4; ++q) {
                        int n = base_n + q;
                        if (acc[q] >= thg[g] && n < N) {
                            int s = atomicAdd(&CNT[row], 1);
                            if (s < CAP) { CV[row][s] = acc[q]; CI[row][s] = n; }
                        }
                    }
                }
            }
        }
    }

    __syncthreads();

    // trim: exact chunk top-6, write part_idx
    if (tid < 64) {
        int cnt = min(CNT[tid], CAP);
        float v[KS]; int ix[KS];
#pragma unroll
        for (int s = 0; s < KS; ++s) { v[s] = -3e38f; ix[s] = 0x7fffffff; }
        for (int s = 0; s < cnt; ++s) {
            float nv = CV[tid][s]; int ni = CI[tid][s];
            if (better(nv, ni, v[KS - 1], ix[KS - 1])) {
                v[KS - 1] = nv; ix[KS - 1] = ni;
#pragma unroll
                for (int j = KS - 1; j > 0; --j) {
                    if (better(v[j], ix[j], v[j - 1], ix[j - 1])) {
                        float tf = v[j]; v[j] = v[j - 1]; v[j - 1] = tf;
                        int   tI = ix[j]; ix[j] = ix[j - 1]; ix[j - 1] = tI;
                    }
                }
            }
        }
        int* dst = part_idx + (size_t)(row0 + tid) * NCAND + ch * KS;
#pragma unroll
        for (int s = 0; s < KS; ++s) dst[s] = ix[s];
    }
}

// ---------- finalize: exact fp32 re-rank, 16 candidates in parallel per wave ----------
__global__ void finalize_kernel(const float* __restrict__ emb,
                                const float* __restrict__ inv_norm,
                                const int* __restrict__ users,
                                const int* __restrict__ pos_items,
                                const int* __restrict__ part_idx,
                                int* __restrict__ out, int Bsz, int N) {
    const int w = threadIdx.x >> 6, lane = threadIdx.x & 63;
    const int b = blockIdx.x * 4 + w;
    if (b >= Bsz) return;
    const int p = pos_items[b], u = users[b];
    const int c = lane & 15, dq = lane >> 4;

    const float4* emb4 = (const float4*)emb;
    const float invp = inv_norm[p];
    float4 a[4];
#pragma unroll
    for (int q = 0; q < 4; ++q) {
        float4 t = emb4[(size_t)p * 16 + dq * 4 + q];
        a[q].x = t.x * invp; a[q].y = t.y * invp;
        a[q].z = t.z * invp; a[q].w = t.w * invp;
    }

    float tv[KH]; int ti_[KH];
#pragma unroll
    for (int s = 0; s < KH; ++s) { tv[s] = -3e38f; ti_[s] = 0x7fffffff; }

    const int* prow = part_idx + (size_t)b * NCAND;

    for (int r = 0; r < NCAND / 16; ++r) {
        int idx = prow[r * 16 + c];
        bool ok = ((unsigned)idx < (unsigned)N) && (idx != p);
        int ic = ok ? idx : 0;
        float dot = 0.f;
#pragma unroll
        for (int q = 0; q < 4; ++q) {
            float4 x = emb4[(size_t)ic * 16 + dq * 4 + q];
            dot += a[q].x * x.x + a[q].y * x.y + a[q].z * x.z + a[q].w * x.w;
        }
        dot += __shfl_xor(dot, 16, 64);
        dot += __shfl_xor(dot, 32, 64);
        float val = ok ? dot * inv_norm[ic] : -3e38f;
        top5_insert(tv, ti_, val, ok ? idx : 0x7fffffff);
    }

#pragma unroll
    for (int m = 1; m <= 8; m <<= 1) {
        float ov[KH]; int oi[KH];
#pragma unroll
        for (int s = 0; s < KH; ++s) {
            ov[s] = __shfl_xor(tv[s], m, 64);
            oi[s] = __shfl_xor(ti_[s], m, 64);
        }
#pragma unroll
        for (int s = 0; s < KH; ++s) top5_insert(tv, ti_, ov[s], oi[s]);
    }

    if (lane == 0) {
        out[b] = u;
        out[Bsz + b] = p;
#pragma unroll
        for (int s = 0; s < KH; ++s) {
            out[2 * Bsz + b * KH + s] = u;
            out[2 * Bsz + KH * Bsz + b * KH + s] = ti_[s];
        }
    }
}

extern "C" void kernel_launch(void* const* d_in, const int* in_sizes, int n_in,
                              void* d_out, int out_size, void* d_ws, size_t ws_size,
                              hipStream_t stream) {
    const int*   users     = (const int*)d_in[0];
    const int*   pos_items = (const int*)d_in[1];
    const float* emb       = (const float*)d_in[3];

    const int B = in_sizes[0];
    const int N = in_sizes[3] / D;

    _Float16* H        = (_Float16*)d_ws;
    float*    inv_norm = (float*)((char*)d_ws + (size_t)N * D * 2);
    int*      part_idx = (int*)((char*)d_ws + (size_t)N * D * 2 + (size_t)N * 4);

    int* out = (int*)d_out;

    hipLaunchKernelGGL(prep_kernel, dim3((N + 15) / 16), dim3(256), 0, stream,
                       emb, H, inv_norm, N);

    hipLaunchKernelGGL(simtopk_kernel, dim3((B / 64) * NCH), dim3(256), 0, stream,
                       H, pos_items, part_idx, N);

    hipLaunchKernelGGL(finalize_kernel, dim3((B + 3) / 4), dim3(256), 0, stream,
                       emb, inv_norm, users, pos_items, part_idx, out, B, N);
}

// Round 7
// 180.365 us; speedup vs baseline: 3.2426x; 3.2426x over previous
//
#include <hip/hip_runtime.h>
#include <hip/hip_bf16.h>

#define D 64
#define KH 5
#define KS 6                        // chunk-list depth: pos + top-5 coverage
#define NCH 64                      // chunks (grid = 32*64 = 2048 blocks, 8/CU)
#define TPC 25                      // tiles per chunk
#define TILE 64
#define CHUNK_ITEMS (TPC * TILE)    // 1600; 64*1600 = 102400 >= N
#define CAP 24                      // candidate cap per (row,chunk)
#define CAPP 25                     // padded stride (odd -> conflict-free)
#define TMP 27                      // TM stride (odd)
#define NCAND (NCH * KS)            // 384 candidates per row at finalize

typedef _Float16 half8 __attribute__((ext_vector_type(8)));
typedef float f32x4 __attribute__((ext_vector_type(4)));

__device__ __forceinline__ bool better(float v, int vi, float w, int wi) {
    return (v > w) || (v == w && vi < wi);
}

__device__ __forceinline__ void top5_insert(float (&v)[KH], int (&ix)[KH], float nv, int ni) {
    if (better(nv, ni, v[KH - 1], ix[KH - 1])) {
        v[KH - 1] = nv; ix[KH - 1] = ni;
#pragma unroll
        for (int j = KH - 1; j > 0; --j) {
            if (better(v[j], ix[j], v[j - 1], ix[j - 1])) {
                float tf = v[j]; v[j] = v[j - 1]; v[j - 1] = tf;
                int   tI = ix[j]; ix[j] = ix[j - 1]; ix[j - 1] = tI;
            }
        }
    }
}

// ---------- prep: normalized fp16 table H[N][64] + fp32 inv_norm[N] ----------
__global__ void prep_kernel(const float* __restrict__ emb,
                            _Float16* __restrict__ H,
                            float* __restrict__ inv_norm, int N) {
    int tid = threadIdx.x;
    int wave = tid >> 6, lane = tid & 63;
    int item = blockIdx.x * 16 + wave * 4 + (lane >> 4);
    if (item >= N) return;
    int g = lane & 15;
    float4 v = reinterpret_cast<const float4*>(emb)[item * 16 + g];
    float ss = v.x * v.x + v.y * v.y + v.z * v.z + v.w * v.w;
#pragma unroll
    for (int m = 1; m < 16; m <<= 1) ss += __shfl_xor(ss, m, 64);
    float inv = 1.0f / fmaxf(sqrtf(ss), 1e-12f);
    union { _Float16 h[4]; uint2 u; } pk;
    pk.h[0] = (_Float16)(v.x * inv);
    pk.h[1] = (_Float16)(v.y * inv);
    pk.h[2] = (_Float16)(v.z * inv);
    pk.h[3] = (_Float16)(v.w * inv);
    reinterpret_cast<uint2*>(H)[item * 16 + g] = pk.u;
    if (g == 0) inv_norm[item] = inv;
}

// ---------- main: two-pass tile-max thresholding (round-4 body, 8 blocks/CU) ----------
// grid 2048 (XCD-swizzled (rowblock, chunk)), block 256 = 4 waves.
__global__ __launch_bounds__(256, 4)
void simtopk_kernel(const _Float16* __restrict__ H,
                    const int* __restrict__ pos_items,
                    int* __restrict__ part_idx, int N) {
    __shared__ float TM[64][TMP];         // tile-max per row (stride 27, odd)
    __shared__ float TH[64];              // per-row threshold (6th tile-max)
    __shared__ float CV[64][CAPP];
    __shared__ int   CI[64][CAPP];
    __shared__ int   CNT[64];

    const int tid = threadIdx.x;
    const int w = tid >> 6, lane = tid & 63;
    const int l15 = lane & 15, l4 = lane >> 4;

    // bijective XCD swizzle: ch%8 == blockIdx%8 == XCD -> L2-local item windows
    const int id = blockIdx.x;
    const int inner = id >> 3;
    const int ch = (id & 7) + 8 * (inner >> 5);
    const int rb = inner & 31;
    const int row0 = rb * 64;
    const int cbeg = ch * CHUNK_ITEMS;

    // B fragments: 4 groups x 16 user rows, register-resident (32 VGPR)
    half8 b0[4], b1[4];
#pragma unroll
    for (int g = 0; g < 4; ++g) {
        int ap = pos_items[row0 + g * 16 + l15];
        const half8* Hrow = (const half8*)(H + (size_t)ap * D);
        b0[g] = Hrow[l4];
        b1[g] = Hrow[4 + l4];
    }

    half8 A[8];
#define LOADA(t)                                                        \
    {                                                                   \
        int ib = cbeg + (t) * TILE;                                     \
        _Pragma("unroll")                                               \
        for (int sub = 0; sub < 4; ++sub) {                             \
            int it = min(ib + sub * 16 + l15, N - 1);                   \
            const half8* hp = (const half8*)(H + (size_t)it * D);       \
            A[2 * sub] = hp[l4];                                        \
            A[2 * sub + 1] = hp[4 + l4];                                \
        }                                                               \
    }

    // ---------------- pass 1: per-(row,tile) max — branchless ----------------
    for (int t = w; t < TPC; t += 4) {
        LOADA(t);
        const int ibase = cbeg + t * TILE;
        const bool ragged = (ibase + TILE > N);
        float rmax[4] = {-3e38f, -3e38f, -3e38f, -3e38f};
#pragma unroll
        for (int sub = 0; sub < 4; ++sub) {
            half8 a0 = A[2 * sub], a1 = A[2 * sub + 1];
            const int base_n = ibase + sub * 16 + 4 * l4;
#pragma unroll
            for (int g = 0; g < 4; ++g) {
                f32x4 z = {0.f, 0.f, 0.f, 0.f};
                f32x4 acc = __builtin_amdgcn_mfma_f32_16x16x32_f16(a0, b0[g], z, 0, 0, 0);
                acc = __builtin_amdgcn_mfma_f32_16x16x32_f16(a1, b1[g], acc, 0, 0, 0);
                if (ragged) {
#pragma unroll
                    for (int q = 0; q < 4; ++q)
                        if (base_n + q >= N) acc[q] = -3e38f;
                }
                rmax[g] = fmaxf(rmax[g],
                          fmaxf(fmaxf(acc[0], acc[1]), fmaxf(acc[2], acc[3])));
            }
        }
#pragma unroll
        for (int g = 0; g < 4; ++g) {
            float m = rmax[g];
            m = fmaxf(m, __shfl_xor(m, 16, 64));
            m = fmaxf(m, __shfl_xor(m, 32, 64));
            if (l4 == 0) TM[g * 16 + l15][t] = m;
        }
    }

    __syncthreads();

    // threshold phase: row's 6th-highest tile-max (values-only sort network)
    if (tid < 64) {
        float v[KS];
#pragma unroll
        for (int s = 0; s < KS; ++s) v[s] = -3e38f;
        for (int t = 0; t < TPC; ++t) {
            float x = TM[tid][t];
            if (x > v[KS - 1]) {
                v[KS - 1] = x;
#pragma unroll
                for (int j = KS - 1; j > 0; --j) {
                    float lo = fminf(v[j], v[j - 1]);
                    v[j - 1] = fmaxf(v[j], v[j - 1]);
                    v[j] = lo;
                }
            }
        }
        TH[tid] = v[KS - 1];
        CNT[tid] = 0;
    }
    __syncthreads();

    float thg[4];
#pragma unroll
    for (int g = 0; g < 4; ++g) thg[g] = TH[g * 16 + l15];

    // ---------------- pass 2: collect scores >= theta (bit-identical MFMA) ----------------
    for (int t = w; t < TPC; t += 4) {
        LOADA(t);
        const int ibase = cbeg + t * TILE;
#pragma unroll
        for (int sub = 0; sub < 4; ++sub) {
            half8 a0 = A[2 * sub], a1 = A[2 * sub + 1];
            const int base_n = ibase + sub * 16 + 4 * l4;
#pragma unroll
            for (int g = 0; g < 4; ++g) {
                f32x4 z = {0.f, 0.f, 0.f, 0.f};
                f32x4 acc = __builtin_amdgcn_mfma_f32_16x16x32_f16(a0, b0[g], z, 0, 0, 0);
                acc = __builtin_amdgcn_mfma_f32_16x16x32_f16(a1, b1[g], acc, 0, 0, 0);
                float m4 = fmaxf(fmaxf(acc[0], acc[1]), fmaxf(acc[2], acc[3]));
                if (m4 >= thg[g]) {
                    const int row = g * 16 + l15;
#pragma unroll
                    for (int q = 0; q < 4; ++q) {
                        int n = base_n + q;
                        if (acc[q] >= thg[g] && n < N) {
                            int s = atomicAdd(&CNT[row], 1);
                            if (s < CAP) { CV[row][s] = acc[q]; CI[row][s] = n; }
                        }
                    }
                }
            }
        }
    }

    __syncthreads();

    // trim: exact chunk top-6, write part_idx
    if (tid < 64) {
        int cnt = min(CNT[tid], CAP);
        float v[KS]; int ix[KS];
#pragma unroll
        for (int s = 0; s < KS; ++s) { v[s] = -3e38f; ix[s] = 0x7fffffff; }
        for (int s = 0; s < cnt; ++s) {
            float nv = CV[tid][s]; int ni = CI[tid][s];
            if (better(nv, ni, v[KS - 1], ix[KS - 1])) {
                v[KS - 1] = nv; ix[KS - 1] = ni;
#pragma unroll
                for (int j = KS - 1; j > 0; --j) {
                    if (better(v[j], ix[j], v[j - 1], ix[j - 1])) {
                        float tf = v[j]; v[j] = v[j - 1]; v[j - 1] = tf;
                        int   tI = ix[j]; ix[j] = ix[j - 1]; ix[j - 1] = tI;
                    }
                }
            }
        }
        int* dst = part_idx + (size_t)(row0 + tid) * NCAND + ch * KS;
#pragma unroll
        for (int s = 0; s < KS; ++s) dst[s] = ix[s];
    }
}

// ---------- finalize: exact fp32 re-rank, 16 candidates in parallel per wave ----------
__global__ void finalize_kernel(const float* __restrict__ emb,
                                const float* __restrict__ inv_norm,
                                const int* __restrict__ users,
                                const int* __restrict__ pos_items,
                                const int* __restrict__ part_idx,
                                int* __restrict__ out, int Bsz, int N) {
    const int w = threadIdx.x >> 6, lane = threadIdx.x & 63;
    const int b = blockIdx.x * 4 + w;
    if (b >= Bsz) return;
    const int p = pos_items[b], u = users[b];
    const int c = lane & 15, dq = lane >> 4;

    const float4* emb4 = (const float4*)emb;
    const float invp = inv_norm[p];
    float4 a[4];
#pragma unroll
    for (int q = 0; q < 4; ++q) {
        float4 t = emb4[(size_t)p * 16 + dq * 4 + q];
        a[q].x = t.x * invp; a[q].y = t.y * invp;
        a[q].z = t.z * invp; a[q].w = t.w * invp;
    }

    float tv[KH]; int ti_[KH];
#pragma unroll
    for (int s = 0; s < KH; ++s) { tv[s] = -3e38f; ti_[s] = 0x7fffffff; }

    const int* prow = part_idx + (size_t)b * NCAND;

    for (int r = 0; r < NCAND / 16; ++r) {
        int idx = prow[r * 16 + c];
        bool ok = ((unsigned)idx < (unsigned)N) && (idx != p);
        int ic = ok ? idx : 0;
        float dot = 0.f;
#pragma unroll
        for (int q = 0; q < 4; ++q) {
            float4 x = emb4[(size_t)ic * 16 + dq * 4 + q];
            dot += a[q].x * x.x + a[q].y * x.y + a[q].z * x.z + a[q].w * x.w;
        }
        dot += __shfl_xor(dot, 16, 64);
        dot += __shfl_xor(dot, 32, 64);
        float val = ok ? dot * inv_norm[ic] : -3e38f;
        top5_insert(tv, ti_, val, ok ? idx : 0x7fffffff);
    }

#pragma unroll
    for (int m = 1; m <= 8; m <<= 1) {
        float ov[KH]; int oi[KH];
#pragma unroll
        for (int s = 0; s < KH; ++s) {
            ov[s] = __shfl_xor(tv[s], m, 64);
            oi[s] = __shfl_xor(ti_[s], m, 64);
        }
#pragma unroll
        for (int s = 0; s < KH; ++s) top5_insert(tv, ti_, ov[s], oi[s]);
    }

    if (lane == 0) {
        out[b] = u;
        out[Bsz + b] = p;
#pragma unroll
        for (int s = 0; s < KH; ++s) {
            out[2 * Bsz + b * KH + s] = u;
            out[2 * Bsz + KH * Bsz + b * KH + s] = ti_[s];
        }
    }
}

extern "C" void kernel_launch(void* const* d_in, const int* in_sizes, int n_in,
                              void* d_out, int out_size, void* d_ws, size_t ws_size,
                              hipStream_t stream) {
    const int*   users     = (const int*)d_in[0];
    const int*   pos_items = (const int*)d_in[1];
    const float* emb       = (const float*)d_in[3];

    const int B = in_sizes[0];
    const int N = in_sizes[3] / D;

    _Float16* H        = (_Float16*)d_ws;
    float*    inv_norm = (float*)((char*)d_ws + (size_t)N * D * 2);
    int*      part_idx = (int*)((char*)d_ws + (size_t)N * D * 2 + (size_t)N * 4);

    int* out = (int*)d_out;

    hipLaunchKernelGGL(prep_kernel, dim3((N + 15) / 16), dim3(256), 0, stream,
                       emb, H, inv_norm, N);

    hipLaunchKernelGGL(simtopk_kernel, dim3((B / 64) * NCH), dim3(256), 0, stream,
                       H, pos_items, part_idx, N);

    hipLaunchKernelGGL(finalize_kernel, dim3((B + 3) / 4), dim3(256), 0, stream,
                       emb, inv_norm, users, pos_items, part_idx, out, B, N);
}

// Round 8
// 176.290 us; speedup vs baseline: 3.3175x; 1.0231x over previous
//
#include <hip/hip_runtime.h>
#include <hip/hip_bf16.h>

#define D 64
#define KH 5
#define KS 6                        // chunk-list depth: pos + top-5 coverage
#define NCH 32                      // chunks
#define TPC 50                      // tiles per chunk
#define TILE 64
#define CHUNK_ITEMS (TPC * TILE)    // 3200; 32*3200 = 102400 >= N
#define CAP 24                      // candidate cap per (row,chunk)
#define CAPP 25                     // CV/CI stride (odd)
#define TMP 53                      // TM stride (odd)
#define NCAND (NCH * KS)            // 192 candidates per row at finalize

typedef _Float16 half8 __attribute__((ext_vector_type(8)));
typedef float f32x4 __attribute__((ext_vector_type(4)));

__device__ __forceinline__ bool better(float v, int vi, float w, int wi) {
    return (v > w) || (v == w && vi < wi);
}

__device__ __forceinline__ void top5_insert(float (&v)[KH], int (&ix)[KH], float nv, int ni) {
    if (better(nv, ni, v[KH - 1], ix[KH - 1])) {
        v[KH - 1] = nv; ix[KH - 1] = ni;
#pragma unroll
        for (int j = KH - 1; j > 0; --j) {
            if (better(v[j], ix[j], v[j - 1], ix[j - 1])) {
                float tf = v[j]; v[j] = v[j - 1]; v[j - 1] = tf;
                int   tI = ix[j]; ix[j] = ix[j - 1]; ix[j - 1] = tI;
            }
        }
    }
}

__device__ __forceinline__ void gload_lds16(const void* g, void* l) {
    __builtin_amdgcn_global_load_lds(
        (const __attribute__((address_space(1))) unsigned int*)g,
        (__attribute__((address_space(3))) unsigned int*)l, 16, 0, 0);
}

// ---------- prep: normalized fp16 table H[N][64] + fp32 inv_norm[N] ----------
__global__ void prep_kernel(const float* __restrict__ emb,
                            _Float16* __restrict__ H,
                            float* __restrict__ inv_norm, int N) {
    int tid = threadIdx.x;
    int wave = tid >> 6, lane = tid & 63;
    int item = blockIdx.x * 16 + wave * 4 + (lane >> 4);
    if (item >= N) return;
    int g = lane & 15;
    float4 v = reinterpret_cast<const float4*>(emb)[item * 16 + g];
    float ss = v.x * v.x + v.y * v.y + v.z * v.z + v.w * v.w;
#pragma unroll
    for (int m = 1; m < 16; m <<= 1) ss += __shfl_xor(ss, m, 64);
    float inv = 1.0f / fmaxf(sqrtf(ss), 1e-12f);
    union { _Float16 h[4]; uint2 u; } pk;
    pk.h[0] = (_Float16)(v.x * inv);
    pk.h[1] = (_Float16)(v.y * inv);
    pk.h[2] = (_Float16)(v.z * inv);
    pk.h[3] = (_Float16)(v.w * inv);
    reinterpret_cast<uint2*>(H)[item * 16 + g] = pk.u;
    if (g == 0) inv_norm[item] = inv;
}

// ---------- main: two-pass tile-max thresholding, LDS-pipelined staging ----------
// grid 1024 (XCD-swizzled (rowblock, chunk)), block 256 = 4 waves, 2 blocks/CU.
// Wave w handles tiles w, w+4, ...; per-wave private 2x8KB LDS double buffer;
// counted vmcnt(8): next tile's 8 loads in flight under current tile's compute.
__global__ __launch_bounds__(256, 2)
void simtopk_kernel(const _Float16* __restrict__ H,
                    const int* __restrict__ pos_items,
                    int* __restrict__ part_idx, int N) {
    // 4x16KB wave dbuf | union{ TM[64][53] | CV[64][25]+CI[64][25] } | TH | CNT
    __shared__ __align__(16) unsigned char SMEM[65536 + TMP * 64 * 4 + 512];
    unsigned char* Bs = SMEM;
    float (*TM)[TMP] = (float (*)[TMP])(SMEM + 65536);           // pass 1
    float* CV  = (float*)(SMEM + 65536);                          // pass 2 [64][25]
    int*   CI  = (int*)(SMEM + 65536 + 64 * CAPP * 4);            //        [64][25]
    float* TH  = (float*)(SMEM + 65536 + TMP * 64 * 4);
    int*   CNT = (int*)(SMEM + 65536 + TMP * 64 * 4 + 256);

    const int tid = threadIdx.x;
    const int w = tid >> 6, lane = tid & 63;
    const int l15 = lane & 15, l4 = lane >> 4;

    // bijective XCD swizzle: ch%8 == blockIdx%8 == XCD -> L2-local item windows
    const int id = blockIdx.x;
    const int inner = id >> 3;
    const int ch = (id & 7) + 8 * (inner >> 5);
    const int rb = inner & 31;
    const int row0 = rb * 64;
    const int cbeg = ch * CHUNK_ITEMS;

    // B fragments: 4 groups x 16 user rows, register-resident (32 VGPR)
    half8 b0[4], b1[4];
#pragma unroll
    for (int g = 0; g < 4; ++g) {
        int ap = pos_items[row0 + g * 16 + l15];
        const half8* Hrow = (const half8*)(H + (size_t)ap * D);
        b0[g] = Hrow[l4];
        b1[g] = Hrow[4 + l4];
    }

    unsigned char* wbuf = Bs + w * 16384;

    // stage one 64-item tile (8KB): linear LDS dest, pre-swizzled global source
#define STAGE(buf, tloc)                                                \
    {                                                                   \
        int ib_ = cbeg + (tloc) * TILE;                                 \
        _Pragma("unroll")                                               \
        for (int i = 0; i < 8; ++i) {                                   \
            int r_ = i * 8 + (lane >> 3);                               \
            int j_ = lane & 7;                                          \
            int grow_ = min(ib_ + r_, N - 1);                           \
            const char* src_ = (const char*)H + (size_t)grow_ * 128 +   \
                               ((j_ ^ (r_ & 7)) << 4);                  \
            gload_lds16(src_, (void*)(wbuf + (buf) * 8192 + i * 1024)); \
        }                                                               \
    }

    // ---------------- pass 1: per-(row,tile) max — branchless ----------------
    {
        int cur = 0;
        STAGE(0, w)
        for (int t = w; t < TPC; t += 4) {
            if (t + 4 < TPC) {
                STAGE(cur ^ 1, t + 4)
                asm volatile("s_waitcnt vmcnt(8)" ::: "memory");
            } else {
                asm volatile("s_waitcnt vmcnt(0)" ::: "memory");
            }
            const unsigned char* base = wbuf + cur * 8192;
            const int ibase = cbeg + t * TILE;
            const bool ragged = (ibase + TILE > N);
            float rmax[4] = {-3e38f, -3e38f, -3e38f, -3e38f};
#pragma unroll
            for (int sub = 0; sub < 4; ++sub) {
                const int r = sub * 16 + l15;
                const int sw = l15 & 7;
                half8 a0 = *(const half8*)(base + r * 128 + ((l4 ^ sw) << 4));
                half8 a1 = *(const half8*)(base + r * 128 + (((4 + l4) ^ sw) << 4));
                const int base_n = ibase + sub * 16 + 4 * l4;
#pragma unroll
                for (int g = 0; g < 4; ++g) {
                    f32x4 z = {0.f, 0.f, 0.f, 0.f};
                    f32x4 acc = __builtin_amdgcn_mfma_f32_16x16x32_f16(a0, b0[g], z, 0, 0, 0);
                    acc = __builtin_amdgcn_mfma_f32_16x16x32_f16(a1, b1[g], acc, 0, 0, 0);
                    if (ragged) {
#pragma unroll
                        for (int q = 0; q < 4; ++q)
                            if (base_n + q >= N) acc[q] = -3e38f;
                    }
                    rmax[g] = fmaxf(rmax[g],
                              fmaxf(fmaxf(acc[0], acc[1]), fmaxf(acc[2], acc[3])));
                }
            }
#pragma unroll
            for (int g = 0; g < 4; ++g) {
                float m = rmax[g];
                m = fmaxf(m, __shfl_xor(m, 16, 64));
                m = fmaxf(m, __shfl_xor(m, 32, 64));
                if (l4 == 0) TM[g * 16 + l15][t] = m;
            }
            cur ^= 1;
        }
    }

    __syncthreads();

    // threshold phase: row's 6th-highest tile-max (values-only sort network)
    float th_val;
    if (tid < 64) {
        float v[KS];
#pragma unroll
        for (int s = 0; s < KS; ++s) v[s] = -3e38f;
        for (int t = 0; t < TPC; ++t) {
            float x = TM[tid][t];
            if (x > v[KS - 1]) {
                v[KS - 1] = x;
#pragma unroll
                for (int j = KS - 1; j > 0; --j) {
                    float lo = fminf(v[j], v[j - 1]);
                    v[j - 1] = fmaxf(v[j], v[j - 1]);
                    v[j] = lo;
                }
            }
        }
        th_val = v[KS - 1];
    }
    __syncthreads();          // TM reads done before CV/CI overwrite the union
    if (tid < 64) {
        TH[tid] = th_val;
        CNT[tid] = 0;
    }
    __syncthreads();

    float thg[4];
#pragma unroll
    for (int g = 0; g < 4; ++g) thg[g] = TH[g * 16 + l15];

    // ---------------- pass 2: collect scores >= theta (bit-identical MFMA) ----------------
    {
        int cur = 0;
        STAGE(0, w)
        for (int t = w; t < TPC; t += 4) {
            if (t + 4 < TPC) {
                STAGE(cur ^ 1, t + 4)
                asm volatile("s_waitcnt vmcnt(8)" ::: "memory");
            } else {
                asm volatile("s_waitcnt vmcnt(0)" ::: "memory");
            }
            const unsigned char* base = wbuf + cur * 8192;
            const int ibase = cbeg + t * TILE;
#pragma unroll
            for (int sub = 0; sub < 4; ++sub) {
                const int r = sub * 16 + l15;
                const int sw = l15 & 7;
                half8 a0 = *(const half8*)(base + r * 128 + ((l4 ^ sw) << 4));
                half8 a1 = *(const half8*)(base + r * 128 + (((4 + l4) ^ sw) << 4));
                const int base_n = ibase + sub * 16 + 4 * l4;
#pragma unroll
                for (int g = 0; g < 4; ++g) {
                    f32x4 z = {0.f, 0.f, 0.f, 0.f};
                    f32x4 acc = __builtin_amdgcn_mfma_f32_16x16x32_f16(a0, b0[g], z, 0, 0, 0);
                    acc = __builtin_amdgcn_mfma_f32_16x16x32_f16(a1, b1[g], acc, 0, 0, 0);
                    float m4 = fmaxf(fmaxf(acc[0], acc[1]), fmaxf(acc[2], acc[3]));
                    if (m4 >= thg[g]) {
                        const int row = g * 16 + l15;
#pragma unroll
                        for (int q = 0; q < 4; ++q) {
                            int n = base_n + q;
                            if (acc[q] >= thg[g] && n < N) {
                                int s = atomicAdd(&CNT[row], 1);
                                if (s < CAP) { CV[row * CAPP + s] = acc[q]; CI[row * CAPP + s] = n; }
                            }
                        }
                    }
                }
            }
            cur ^= 1;
        }
    }

    __syncthreads();

    // trim: exact chunk top-6, write part_idx
    if (tid < 64) {
        int cnt = min(CNT[tid], CAP);
        float v[KS]; int ix[KS];
#pragma unroll
        for (int s = 0; s < KS; ++s) { v[s] = -3e38f; ix[s] = 0x7fffffff; }
        for (int s = 0; s < cnt; ++s) {
            float nv = CV[tid * CAPP + s]; int ni = CI[tid * CAPP + s];
            if (better(nv, ni, v[KS - 1], ix[KS - 1])) {
                v[KS - 1] = nv; ix[KS - 1] = ni;
#pragma unroll
                for (int j = KS - 1; j > 0; --j) {
                    if (better(v[j], ix[j], v[j - 1], ix[j - 1])) {
                        float tf = v[j]; v[j] = v[j - 1]; v[j - 1] = tf;
                        int   tI = ix[j]; ix[j] = ix[j - 1]; ix[j - 1] = tI;
                    }
                }
            }
        }
        int* dst = part_idx + (size_t)(row0 + tid) * NCAND + ch * KS;
#pragma unroll
        for (int s = 0; s < KS; ++s) dst[s] = ix[s];
    }
}

// ---------- finalize: exact fp32 re-rank, 16 candidates in parallel per wave ----------
__global__ void finalize_kernel(const float* __restrict__ emb,
                                const float* __restrict__ inv_norm,
                                const int* __restrict__ users,
                                const int* __restrict__ pos_items,
                                const int* __restrict__ part_idx,
                                int* __restrict__ out, int Bsz, int N) {
    const int w = threadIdx.x >> 6, lane = threadIdx.x & 63;
    const int b = blockIdx.x * 4 + w;
    if (b >= Bsz) return;
    const int p = pos_items[b], u = users[b];
    const int c = lane & 15, dq = lane >> 4;

    const float4* emb4 = (const float4*)emb;
    const float invp = inv_norm[p];
    float4 a[4];
#pragma unroll
    for (int q = 0; q < 4; ++q) {
        float4 t = emb4[(size_t)p * 16 + dq * 4 + q];
        a[q].x = t.x * invp; a[q].y = t.y * invp;
        a[q].z = t.z * invp; a[q].w = t.w * invp;
    }

    float tv[KH]; int ti_[KH];
#pragma unroll
    for (int s = 0; s < KH; ++s) { tv[s] = -3e38f; ti_[s] = 0x7fffffff; }

    const int* prow = part_idx + (size_t)b * NCAND;

    for (int r = 0; r < NCAND / 16; ++r) {
        int idx = prow[r * 16 + c];
        bool ok = ((unsigned)idx < (unsigned)N) && (idx != p);
        int ic = ok ? idx : 0;
        float dot = 0.f;
#pragma unroll
        for (int q = 0; q < 4; ++q) {
            float4 x = emb4[(size_t)ic * 16 + dq * 4 + q];
            dot += a[q].x * x.x + a[q].y * x.y + a[q].z * x.z + a[q].w * x.w;
        }
        dot += __shfl_xor(dot, 16, 64);
        dot += __shfl_xor(dot, 32, 64);
        float val = ok ? dot * inv_norm[ic] : -3e38f;
        top5_insert(tv, ti_, val, ok ? idx : 0x7fffffff);
    }

#pragma unroll
    for (int m = 1; m <= 8; m <<= 1) {
        float ov[KH]; int oi[KH];
#pragma unroll
        for (int s = 0; s < KH; ++s) {
            ov[s] = __shfl_xor(tv[s], m, 64);
            oi[s] = __shfl_xor(ti_[s], m, 64);
        }
#pragma unroll
        for (int s = 0; s < KH; ++s) top5_insert(tv, ti_, ov[s], oi[s]);
    }

    if (lane == 0) {
        out[b] = u;
        out[Bsz + b] = p;
#pragma unroll
        for (int s = 0; s < KH; ++s) {
            out[2 * Bsz + b * KH + s] = u;
            out[2 * Bsz + KH * Bsz + b * KH + s] = ti_[s];
        }
    }
}

extern "C" void kernel_launch(void* const* d_in, const int* in_sizes, int n_in,
                              void* d_out, int out_size, void* d_ws, size_t ws_size,
                              hipStream_t stream) {
    const int*   users     = (const int*)d_in[0];
    const int*   pos_items = (const int*)d_in[1];
    const float* emb       = (const float*)d_in[3];

    const int B = in_sizes[0];
    const int N = in_sizes[3] / D;

    _Float16* H        = (_Float16*)d_ws;
    float*    inv_norm = (float*)((char*)d_ws + (size_t)N * D * 2);
    int*      part_idx = (int*)((char*)d_ws + (size_t)N * D * 2 + (size_t)N * 4);

    int* out = (int*)d_out;

    hipLaunchKernelGGL(prep_kernel, dim3((N + 15) / 16), dim3(256), 0, stream,
                       emb, H, inv_norm, N);

    hipLaunchKernelGGL(simtopk_kernel, dim3((B / 64) * NCH), dim3(256), 0, stream,
                       H, pos_items, part_idx, N);

    hipLaunchKernelGGL(finalize_kernel, dim3((B + 3) / 4), dim3(256), 0, stream,
                       emb, inv_norm, users, pos_items, part_idx, out, B, N);
}

// Round 9
// 158.136 us; speedup vs baseline: 3.6984x; 1.1148x over previous
//
#include <hip/hip_runtime.h>
#include <hip/hip_bf16.h>

#define D 64
#define KH 5
#define KS 6                        // chunk-list depth: pos + top-5 coverage
#define NCH 32                      // chunks
#define TPC 50                      // tiles per chunk
#define TILE 64
#define CHUNK_ITEMS (TPC * TILE)    // 3200; 32*3200 = 102400 >= N
#define BMROWS 128                  // user-rows per block (8 groups of 16)
#define NG 8                        // B groups
#define CAP 24                      // candidate cap per (row,chunk)
#define CAPP 25                     // CV/CI stride
#define TMP 53                      // TM stride (odd)
#define NCAND (NCH * KS)            // 192 candidates per row at finalize

typedef _Float16 half8 __attribute__((ext_vector_type(8)));
typedef float f32x4 __attribute__((ext_vector_type(4)));

__device__ __forceinline__ bool better(float v, int vi, float w, int wi) {
    return (v > w) || (v == w && vi < wi);
}

__device__ __forceinline__ void top5_insert(float (&v)[KH], int (&ix)[KH], float nv, int ni) {
    if (better(nv, ni, v[KH - 1], ix[KH - 1])) {
        v[KH - 1] = nv; ix[KH - 1] = ni;
#pragma unroll
        for (int j = KH - 1; j > 0; --j) {
            if (better(v[j], ix[j], v[j - 1], ix[j - 1])) {
                float tf = v[j]; v[j] = v[j - 1]; v[j - 1] = tf;
                int   tI = ix[j]; ix[j] = ix[j - 1]; ix[j - 1] = tI;
            }
        }
    }
}

// ---------- prep: normalized fp16 table H[N][64] + fp32 inv_norm[N] ----------
__global__ void prep_kernel(const float* __restrict__ emb,
                            _Float16* __restrict__ H,
                            float* __restrict__ inv_norm, int N) {
    int tid = threadIdx.x;
    int wave = tid >> 6, lane = tid & 63;
    int item = blockIdx.x * 16 + wave * 4 + (lane >> 4);
    if (item >= N) return;
    int g = lane & 15;
    float4 v = reinterpret_cast<const float4*>(emb)[item * 16 + g];
    float ss = v.x * v.x + v.y * v.y + v.z * v.z + v.w * v.w;
#pragma unroll
    for (int m = 1; m < 16; m <<= 1) ss += __shfl_xor(ss, m, 64);
    float inv = 1.0f / fmaxf(sqrtf(ss), 1e-12f);
    union { _Float16 h[4]; uint2 u; } pk;
    pk.h[0] = (_Float16)(v.x * inv);
    pk.h[1] = (_Float16)(v.y * inv);
    pk.h[2] = (_Float16)(v.z * inv);
    pk.h[3] = (_Float16)(v.w * inv);
    reinterpret_cast<uint2*>(H)[item * 16 + g] = pk.u;
    if (g == 0) inv_norm[item] = inv;
}

// ---------- main: two-pass tile-max thresholding, 128 rows/block ----------
// grid 512 (XCD-swizzled (rowblock, chunk)), block 256 = 4 waves.
// Wave w handles tiles w, w+4, ...; 128 pos rows (8 groups) register-resident.
__global__ __launch_bounds__(256, 2)
void simtopk_kernel(const _Float16* __restrict__ H,
                    const int* __restrict__ pos_items,
                    int* __restrict__ part_idx, int N) {
    // union{ TM[128][53] | CV[128][25]+CI[128][25] } + TH[128] + CNT[128]
    __shared__ __align__(16) unsigned char SMEM[BMROWS * TMP * 4 + 1024];
    float (*TM)[TMP] = (float (*)[TMP])(SMEM);
    float* CV  = (float*)(SMEM);                       // [128][25]
    int*   CI  = (int*)(SMEM + BMROWS * CAPP * 4);     // [128][25]
    float* TH  = (float*)(SMEM + BMROWS * TMP * 4);
    int*   CNT = (int*)(SMEM + BMROWS * TMP * 4 + 512);

    const int tid = threadIdx.x;
    const int w = tid >> 6, lane = tid & 63;
    const int l15 = lane & 15, l4 = lane >> 4;

    // bijective XCD swizzle: ch%8 == blockIdx%8 == XCD -> L2-local item windows
    const int id = blockIdx.x;           // [0,512)
    const int inner = id >> 3;           // [0,64)
    const int ch = (id & 7) + 8 * (inner >> 4);   // [0,32)
    const int rb = inner & 15;           // [0,16)
    const int row0 = rb * BMROWS;
    const int cbeg = ch * CHUNK_ITEMS;

    // B fragments: 8 groups x 16 user rows, register-resident (64 VGPR)
    half8 b0[NG], b1[NG];
#pragma unroll
    for (int g = 0; g < NG; ++g) {
        int ap = pos_items[row0 + g * 16 + l15];
        const half8* Hrow = (const half8*)(H + (size_t)ap * D);
        b0[g] = Hrow[l4];
        b1[g] = Hrow[4 + l4];
    }

    half8 A[8];
#define LOADA(t)                                                        \
    {                                                                   \
        int ib = cbeg + (t) * TILE;                                     \
        _Pragma("unroll")                                               \
        for (int sub = 0; sub < 4; ++sub) {                             \
            int it = min(ib + sub * 16 + l15, N - 1);                   \
            const half8* hp = (const half8*)(H + (size_t)it * D);       \
            A[2 * sub] = hp[l4];                                        \
            A[2 * sub + 1] = hp[4 + l4];                                \
        }                                                               \
    }

    // ---------------- pass 1: per-(row,tile) max — branchless ----------------
    for (int t = w; t < TPC; t += 4) {
        LOADA(t);
        const int ibase = cbeg + t * TILE;
        const bool ragged = (ibase + TILE > N);
        float rmax[NG];
#pragma unroll
        for (int g = 0; g < NG; ++g) rmax[g] = -3e38f;
#pragma unroll
        for (int sub = 0; sub < 4; ++sub) {
            half8 a0 = A[2 * sub], a1 = A[2 * sub + 1];
            const int base_n = ibase + sub * 16 + 4 * l4;
#pragma unroll
            for (int g = 0; g < NG; ++g) {
                f32x4 z = {0.f, 0.f, 0.f, 0.f};
                f32x4 acc = __builtin_amdgcn_mfma_f32_16x16x32_f16(a0, b0[g], z, 0, 0, 0);
                acc = __builtin_amdgcn_mfma_f32_16x16x32_f16(a1, b1[g], acc, 0, 0, 0);
                if (ragged) {
#pragma unroll
                    for (int q = 0; q < 4; ++q)
                        if (base_n + q >= N) acc[q] = -3e38f;
                }
                rmax[g] = fmaxf(rmax[g],
                          fmaxf(fmaxf(acc[0], acc[1]), fmaxf(acc[2], acc[3])));
            }
        }
#pragma unroll
        for (int g = 0; g < NG; ++g) {
            float m = rmax[g];
            m = fmaxf(m, __shfl_xor(m, 16, 64));
            m = fmaxf(m, __shfl_xor(m, 32, 64));
            if (l4 == 0) TM[g * 16 + l15][t] = m;
        }
    }

    __syncthreads();

    // threshold phase: row's 6th-highest tile-max (values-only sort network)
    float th_val;
    if (tid < BMROWS) {
        float v[KS];
#pragma unroll
        for (int s = 0; s < KS; ++s) v[s] = -3e38f;
        for (int t = 0; t < TPC; ++t) {
            float x = TM[tid][t];
            if (x > v[KS - 1]) {
                v[KS - 1] = x;
#pragma unroll
                for (int j = KS - 1; j > 0; --j) {
                    float lo = fminf(v[j], v[j - 1]);
                    v[j - 1] = fmaxf(v[j], v[j - 1]);
                    v[j] = lo;
                }
            }
        }
        th_val = v[KS - 1];
    }
    __syncthreads();          // TM reads done before CV/CI overwrite the union
    if (tid < BMROWS) {
        TH[tid] = th_val;
        CNT[tid] = 0;
    }
    __syncthreads();

    float thg[NG];
#pragma unroll
    for (int g = 0; g < NG; ++g) thg[g] = TH[g * 16 + l15];

    // ---------------- pass 2: collect scores >= theta (bit-identical MFMA) ----------------
    for (int t = w; t < TPC; t += 4) {
        LOADA(t);
        const int ibase = cbeg + t * TILE;
#pragma unroll
        for (int sub = 0; sub < 4; ++sub) {
            half8 a0 = A[2 * sub], a1 = A[2 * sub + 1];
            const int base_n = ibase + sub * 16 + 4 * l4;
#pragma unroll
            for (int g = 0; g < NG; ++g) {
                f32x4 z = {0.f, 0.f, 0.f, 0.f};
                f32x4 acc = __builtin_amdgcn_mfma_f32_16x16x32_f16(a0, b0[g], z, 0, 0, 0);
                acc = __builtin_amdgcn_mfma_f32_16x16x32_f16(a1, b1[g], acc, 0, 0, 0);
                float m4 = fmaxf(fmaxf(acc[0], acc[1]), fmaxf(acc[2], acc[3]));
                if (m4 >= thg[g]) {
                    const int row = g * 16 + l15;
#pragma unroll
                    for (int q = 0; q < 4; ++q) {
                        int n = base_n + q;
                        if (acc[q] >= thg[g] && n < N) {
                            int s = atomicAdd(&CNT[row], 1);
                            if (s < CAP) { CV[row * CAPP + s] = acc[q]; CI[row * CAPP + s] = n; }
                        }
                    }
                }
            }
        }
    }

    __syncthreads();

    // trim: exact chunk top-6, write part_idx
    if (tid < BMROWS) {
        int cnt = min(CNT[tid], CAP);
        float v[KS]; int ix[KS];
#pragma unroll
        for (int s = 0; s < KS; ++s) { v[s] = -3e38f; ix[s] = 0x7fffffff; }
        for (int s = 0; s < cnt; ++s) {
            float nv = CV[tid * CAPP + s]; int ni = CI[tid * CAPP + s];
            if (better(nv, ni, v[KS - 1], ix[KS - 1])) {
                v[KS - 1] = nv; ix[KS - 1] = ni;
#pragma unroll
                for (int j = KS - 1; j > 0; --j) {
                    if (better(v[j], ix[j], v[j - 1], ix[j - 1])) {
                        float tf = v[j]; v[j] = v[j - 1]; v[j - 1] = tf;
                        int   tI = ix[j]; ix[j] = ix[j - 1]; ix[j - 1] = tI;
                    }
                }
            }
        }
        int* dst = part_idx + (size_t)(row0 + tid) * NCAND + ch * KS;
#pragma unroll
        for (int s = 0; s < KS; ++s) dst[s] = ix[s];
    }
}

// ---------- finalize: exact fp32 re-rank, 16 candidates in parallel per wave ----------
__global__ void finalize_kernel(const float* __restrict__ emb,
                                const float* __restrict__ inv_norm,
                                const int* __restrict__ users,
                                const int* __restrict__ pos_items,
                                const int* __restrict__ part_idx,
                                int* __restrict__ out, int Bsz, int N) {
    const int w = threadIdx.x >> 6, lane = threadIdx.x & 63;
    const int b = blockIdx.x * 4 + w;
    if (b >= Bsz) return;
    const int p = pos_items[b], u = users[b];
    const int c = lane & 15, dq = lane >> 4;

    const float4* emb4 = (const float4*)emb;
    const float invp = inv_norm[p];
    float4 a[4];
#pragma unroll
    for (int q = 0; q < 4; ++q) {
        float4 t = emb4[(size_t)p * 16 + dq * 4 + q];
        a[q].x = t.x * invp; a[q].y = t.y * invp;
        a[q].z = t.z * invp; a[q].w = t.w * invp;
    }

    float tv[KH]; int ti_[KH];
#pragma unroll
    for (int s = 0; s < KH; ++s) { tv[s] = -3e38f; ti_[s] = 0x7fffffff; }

    const int* prow = part_idx + (size_t)b * NCAND;

    for (int r = 0; r < NCAND / 16; ++r) {
        int idx = prow[r * 16 + c];
        bool ok = ((unsigned)idx < (unsigned)N) && (idx != p);
        int ic = ok ? idx : 0;
        float dot = 0.f;
#pragma unroll
        for (int q = 0; q < 4; ++q) {
            float4 x = emb4[(size_t)ic * 16 + dq * 4 + q];
            dot += a[q].x * x.x + a[q].y * x.y + a[q].z * x.z + a[q].w * x.w;
        }
        dot += __shfl_xor(dot, 16, 64);
        dot += __shfl_xor(dot, 32, 64);
        float val = ok ? dot * inv_norm[ic] : -3e38f;
        top5_insert(tv, ti_, val, ok ? idx : 0x7fffffff);
    }

#pragma unroll
    for (int m = 1; m <= 8; m <<= 1) {
        float ov[KH]; int oi[KH];
#pragma unroll
        for (int s = 0; s < KH; ++s) {
            ov[s] = __shfl_xor(tv[s], m, 64);
            oi[s] = __shfl_xor(ti_[s], m, 64);
        }
#pragma unroll
        for (int s = 0; s < KH; ++s) top5_insert(tv, ti_, ov[s], oi[s]);
    }

    if (lane == 0) {
        out[b] = u;
        out[Bsz + b] = p;
#pragma unroll
        for (int s = 0; s < KH; ++s) {
            out[2 * Bsz + b * KH + s] = u;
            out[2 * Bsz + KH * Bsz + b * KH + s] = ti_[s];
        }
    }
}

extern "C" void kernel_launch(void* const* d_in, const int* in_sizes, int n_in,
                              void* d_out, int out_size, void* d_ws, size_t ws_size,
                              hipStream_t stream) {
    const int*   users     = (const int*)d_in[0];
    const int*   pos_items = (const int*)d_in[1];
    const float* emb       = (const float*)d_in[3];

    const int B = in_sizes[0];
    const int N = in_sizes[3] / D;

    _Float16* H        = (_Float16*)d_ws;
    float*    inv_norm = (float*)((char*)d_ws + (size_t)N * D * 2);
    int*      part_idx = (int*)((char*)d_ws + (size_t)N * D * 2 + (size_t)N * 4);

    int* out = (int*)d_out;

    hipLaunchKernelGGL(prep_kernel, dim3((N + 15) / 16), dim3(256), 0, stream,
                       emb, H, inv_norm, N);

    hipLaunchKernelGGL(simtopk_kernel, dim3((B / BMROWS) * NCH), dim3(256), 0, stream,
                       H, pos_items, part_idx, N);

    hipLaunchKernelGGL(finalize_kernel, dim3((B + 3) / 4), dim3(256), 0, stream,
                       emb, inv_norm, users, pos_items, part_idx, out, B, N);
}